// Round 4
// baseline (168.596 us; speedup 1.0000x reference)
//
#include <hip/hip_runtime.h>

// GraphConv: out[b,i,c] = relu( VW[b,0,i,c] + sum_{j,l} A[b,i,j,l] * VW[b,l+1,j,c] )
// VW[b,l,j,c] = sum_f V[b,j,f] h[l,c,f]
// K2 key fact: flattening A's (j,l) axes gives contiguous K=4096 with k=j*4+l.
// R4: K2 is LDS-free — A has zero intra-block reuse, so fragments are loaded
// straight from global (full-line-use gathers), converted in-register. No
// barriers; latency hidden by 4 waves/SIMD (launch_bounds(512,4)) + unroll-8 ILP.

typedef float          f32x4  __attribute__((ext_vector_type(4)));
typedef __bf16         bf16x8 __attribute__((ext_vector_type(8)));
typedef unsigned short u16x4  __attribute__((ext_vector_type(4)));
typedef unsigned int   u32x4  __attribute__((ext_vector_type(4)));

#define DEV __device__ __forceinline__

DEV void cvt8(__bf16* d, f32x4 u, f32x4 v) {
  bf16x8 o;
  o[0]=(__bf16)u[0]; o[1]=(__bf16)u[1]; o[2]=(__bf16)u[2]; o[3]=(__bf16)u[3];
  o[4]=(__bf16)v[0]; o[5]=(__bf16)v[1]; o[6]=(__bf16)v[2]; o[7]=(__bf16)v[3];
  *(bf16x8*)d = o;
}

DEV bf16x8 cvt8r(f32x4 u, f32x4 v) {
  bf16x8 o;
  o[0]=(__bf16)u[0]; o[1]=(__bf16)u[1]; o[2]=(__bf16)u[2]; o[3]=(__bf16)u[3];
  o[4]=(__bf16)v[0]; o[5]=(__bf16)v[1]; o[6]=(__bf16)v[2]; o[7]=(__bf16)v[3];
  return o;
}

DEV unsigned short bfbits(float x) {
  return __builtin_bit_cast(unsigned short, (__bf16)x);
}

// ---------------------------------------------------------------------------
// K1: VW projection.  Per block: (b, j-tile 128, c-tile 64), all 5 l.
// M-axis = c (16-dim rows), N-axis = j, K = f (256, 4 steps of 64).
// Writes W2t[b][c][j*4 + (l-1)] bf16 (packed 4xl per store) and VW0[b][j][c] f32.
// ---------------------------------------------------------------------------
__global__ __launch_bounds__(512, 2)
void k1_vw(const float* __restrict__ Vg, const float* __restrict__ Hg,
           unsigned short* __restrict__ W2t, float* __restrict__ VW0)
{
  __shared__ __attribute__((aligned(16))) __bf16 Vs[2][128*64];  // 2 x 16 KB
  __shared__ __attribute__((aligned(16))) __bf16 Hs[2][320*64];  // 2 x 40 KB

  const int tid  = threadIdx.x;
  const int lane = tid & 63;
  const int wid  = tid >> 6;   // 0..7
  const int wj   = wid >> 1;   // 0..3 (j strips of 32)
  const int wc   = wid & 1;    // 0..1 (c strips of 32)
  const int li   = lane & 15;
  const int lg   = lane >> 4;

  const int bid = blockIdx.x;
  const int ct  = bid & 3;
  const int jt  = (bid >> 2) & 7;
  const int b   = bid >> 5;
  const int j0  = jt * 128;
  const int c0  = ct * 64;

  const float* sptr[7];
  int sdst[7];
#pragma unroll
  for (int r = 0; r < 2; ++r) {
    int n = r*512 + tid, row = n >> 3, q = n & 7;
    sptr[r] = Vg + (size_t)(b*1024 + j0 + row)*256 + q*8;
    sdst[r] = row*64 + ((q ^ (row & 7))*8);
  }
#pragma unroll
  for (int r = 0; r < 5; ++r) {
    int n = r*512 + tid, row = n >> 3, q = n & 7;
    int l = row >> 6, cl = row & 63;
    sptr[2+r] = Hg + (size_t)(l*256 + c0 + cl)*256 + q*8;
    sdst[2+r] = row*64 + ((q ^ (row & 7))*8);
  }

  f32x4 acc[5][2][2];
#pragma unroll
  for (int l=0;l<5;l++)
#pragma unroll
    for (int x=0;x<2;x++)
#pragma unroll
      for (int y=0;y<2;y++) acc[l][x][y] = (f32x4){0.f,0.f,0.f,0.f};

  {
    f32x4 sa[14];
#pragma unroll
    for (int i=0;i<7;i++) { sa[2*i] = *(const f32x4*)(sptr[i]); sa[2*i+1] = *(const f32x4*)(sptr[i]+4); }
#pragma unroll
    for (int i=0;i<7;i++) {
      __bf16* d = (i < 2) ? &Vs[0][sdst[i]] : &Hs[0][sdst[i]];
      cvt8(d, sa[2*i], sa[2*i+1]);
    }
  }
  __syncthreads();

  int cur = 0;
#pragma unroll 1
  for (int t = 0; t < 4; ++t) {
    const int nxt = cur ^ 1;
    f32x4 sa[14];
    if (t < 3) {
      const int ko = (t+1)*64;
#pragma unroll
      for (int i=0;i<7;i++) { sa[2*i] = *(const f32x4*)(sptr[i]+ko); sa[2*i+1] = *(const f32x4*)(sptr[i]+ko+4); }
    }
    const __bf16* Vsc = &Vs[cur][0];
    const __bf16* Hsc = &Hs[cur][0];
#pragma unroll
    for (int ks = 0; ks < 2; ++ks) {
      bf16x8 hf[10], vf[2];
#pragma unroll
      for (int l=0;l<5;l++)
#pragma unroll
        for (int cm=0;cm<2;cm++) {
          int row = l*64 + wc*32 + cm*16 + li;
          int ch  = (ks*4 + lg) ^ (row & 7);
          hf[l*2+cm] = *(const bf16x8*)(Hsc + row*64 + ch*8);
        }
#pragma unroll
      for (int jn=0;jn<2;jn++) {
        int row = wj*32 + jn*16 + li;
        int ch  = (ks*4 + lg) ^ (row & 7);
        vf[jn] = *(const bf16x8*)(Vsc + row*64 + ch*8);
      }
#pragma unroll
      for (int l=0;l<5;l++)
#pragma unroll
        for (int cm=0;cm<2;cm++)
#pragma unroll
          for (int jn=0;jn<2;jn++)
            acc[l][cm][jn] = __builtin_amdgcn_mfma_f32_16x16x32_bf16(
                hf[l*2+cm], vf[jn], acc[l][cm][jn], 0, 0, 0);
    }
    if (t < 3) {
#pragma unroll
      for (int i=0;i<7;i++) {
        __bf16* d = (i < 2) ? &Vs[nxt][sdst[i]] : &Hs[nxt][sdst[i]];
        cvt8(d, sa[2*i], sa[2*i+1]);
      }
    }
    __syncthreads();
    cur = nxt;
  }

#pragma unroll
  for (int cm=0;cm<2;cm++)
#pragma unroll
    for (int r=0;r<4;r++) {
      const int c = c0 + wc*32 + cm*16 + lg*4 + r;
#pragma unroll
      for (int jn=0;jn<2;jn++) {
        const int j = j0 + wj*32 + jn*16 + li;
        u16x4 pk;
        pk[0] = bfbits(acc[1][cm][jn][r]);
        pk[1] = bfbits(acc[2][cm][jn][r]);
        pk[2] = bfbits(acc[3][cm][jn][r]);
        pk[3] = bfbits(acc[4][cm][jn][r]);
        *(u16x4*)(W2t + (size_t)(b*256 + c)*4096 + (size_t)j*4) = pk;
        VW0[(size_t)(b*1024 + j)*256 + c] = acc[0][cm][jn][r];
      }
    }
}

// ---------------------------------------------------------------------------
// K2: partial[kt][b][i][c] = sum_{k in chunk} A[b][i][k] * W2t[b][c][k]
// LDS-free. tile 128(i) x 128(c), k-split 4, grid 512, 512 thr (8 waves).
// Wave = 64i x 32c: m=0..3 (i 16-strips), n=0..1 (c 16-strips), acc 8xf32x4.
// Per k-step (32): 8x f32x4 A gathers (full 64B-line use), 2x bf16x8 B loads,
// in-register f32->bf16 cvt, 8 MFMA. No barriers; compiler pipelines unroll-8.
// launch_bounds(512,4): VGPR<=128 -> 2 blocks/CU = 4 waves/SIMD.
// XCD swizzle: each XCD owns one batch b (A ct-pair reuse hits its L2).
// ---------------------------------------------------------------------------
__global__ __launch_bounds__(512, 4)
void k2_gemm(const float* __restrict__ Ag, const unsigned short* __restrict__ W2t,
             unsigned short* __restrict__ part)
{
  const int tid  = threadIdx.x;
  const int lane = tid & 63;
  const int wid  = tid >> 6;   // 0..7
  const int wi   = wid >> 2;   // 0..1 (i 64-strips)
  const int wc   = wid & 3;    // 0..3 (c 32-strips)
  const int li   = lane & 15;
  const int lg   = lane >> 4;

  // XCD swizzle: physical p -> logical bid; each XCD (p&7) owns batch b=(p&7).
  const int p   = blockIdx.x;               // 512 blocks
  const int bid = (p & 7) * 64 + (p >> 3);
  const int ct  = bid & 1;
  const int kt  = (bid >> 1) & 3;
  const int it  = (bid >> 3) & 7;
  const int b   = bid >> 6;

  const int i0 = it*128, c0 = ct*128, k0 = kt*1024;

  const float* pA[4];
#pragma unroll
  for (int m=0;m<4;m++)
    pA[m] = Ag + (size_t)(b*1024 + i0 + wi*64 + m*16 + li)*4096 + k0 + lg*8;
  const unsigned short* pB[2];
#pragma unroll
  for (int n=0;n<2;n++)
    pB[n] = W2t + (size_t)(b*256 + c0 + wc*32 + n*16 + li)*4096 + k0 + lg*8;

  f32x4 acc[4][2];
#pragma unroll
  for (int m=0;m<4;m++)
#pragma unroll
    for (int n=0;n<2;n++) acc[m][n] = (f32x4){0.f,0.f,0.f,0.f};

#pragma unroll 1
  for (int o = 0; o < 4; ++o) {
#pragma unroll
    for (int s = 0; s < 8; ++s) {
      bf16x8 af[4], bf[2];
#pragma unroll
      for (int m=0;m<4;m++) {
        f32x4 lo = *(const f32x4*)(pA[m] + s*32);
        f32x4 hi = *(const f32x4*)(pA[m] + s*32 + 4);
        af[m] = cvt8r(lo, hi);
      }
#pragma unroll
      for (int n=0;n<2;n++)
        bf[n] = *(const bf16x8*)(pB[n] + s*32);
#pragma unroll
      for (int m=0;m<4;m++)
#pragma unroll
        for (int n=0;n<2;n++)
          acc[m][n] = __builtin_amdgcn_mfma_f32_16x16x32_bf16(af[m], bf[n], acc[m][n], 0, 0, 0);
    }
#pragma unroll
    for (int m=0;m<4;m++) pA[m] += 256;   // 8 steps * 32 k (floats)
#pragma unroll
    for (int n=0;n<2;n++) pB[n] += 256;   // 8 steps * 32 k (shorts)
  }

  // epilogue -> bf16 partial plane
  unsigned short* pb = part + (size_t)kt*2097152u + (size_t)(b*1024 + i0)*256 + c0;
#pragma unroll
  for (int m=0;m<4;m++)
#pragma unroll
    for (int r=0;r<4;r++) {
      const int il = wi*64 + m*16 + lg*4 + r;
#pragma unroll
      for (int n=0;n<2;n++) {
        const int cl = wc*32 + n*16 + li;
        pb[(size_t)il*256 + cl] = bfbits(acc[m][n][r]);
      }
    }
}

// ---------------------------------------------------------------------------
// K3: out = relu(VW0 + sum_{kt} partial[kt]), 8 elems/thread
// ---------------------------------------------------------------------------
__global__ __launch_bounds__(256)
void k3_reduce(const unsigned short* __restrict__ part, const float* __restrict__ VW0,
               float* __restrict__ out)
{
  const size_t i8 = ((size_t)blockIdx.x*256 + threadIdx.x)*8;
  f32x4 s0 = *(const f32x4*)(VW0 + i8);
  f32x4 s1 = *(const f32x4*)(VW0 + i8 + 4);
#pragma unroll
  for (int p=0;p<4;p++) {
    u32x4 u = *(const u32x4*)(part + (size_t)p*2097152u + i8);
    s0[0] += __uint_as_float(u[0] << 16);  s0[1] += __uint_as_float(u[0] & 0xffff0000u);
    s0[2] += __uint_as_float(u[1] << 16);  s0[3] += __uint_as_float(u[1] & 0xffff0000u);
    s1[0] += __uint_as_float(u[2] << 16);  s1[1] += __uint_as_float(u[2] & 0xffff0000u);
    s1[2] += __uint_as_float(u[3] << 16);  s1[3] += __uint_as_float(u[3] & 0xffff0000u);
  }
#pragma unroll
  for (int e=0;e<4;e++){ s0[e] = fmaxf(s0[e],0.f); s1[e] = fmaxf(s1[e],0.f); }
  *(f32x4*)(out + i8)     = s0;
  *(f32x4*)(out + i8 + 4) = s1;
}

// ---------------------------------------------------------------------------
extern "C" void kernel_launch(void* const* d_in, const int* in_sizes, int n_in,
                              void* d_out, int out_size, void* d_ws, size_t ws_size,
                              hipStream_t stream) {
  const float* Vg = (const float*)d_in[0];   // (8,1024,256) f32
  const float* Ag = (const float*)d_in[1];   // (8,1024,1024,4) f32
  const float* Hg = (const float*)d_in[2];   // (5,256,256) f32
  float* out = (float*)d_out;                // (8,1024,256) f32

  if (ws_size < 41943040u) return;
  char* ws = (char*)d_ws;
  unsigned short* W2t  = (unsigned short*)(ws);
  float*          VW0  = (float*)(ws + 16777216u);
  unsigned short* part = (unsigned short*)(ws + 16777216u + 8388608u);

  k1_vw   <<<dim3(256),  dim3(512), 0, stream>>>(Vg, Hg, W2t, VW0);
  k2_gemm <<<dim3(512),  dim3(512), 0, stream>>>(Ag, W2t, part);
  k3_reduce<<<dim3(1024), dim3(256), 0, stream>>>(part, VW0, out);
}

// Round 5
// 56.604 us; speedup vs baseline: 2.9785x; 2.9785x over previous
//
#include <hip/hip_runtime.h>

// GraphConv: out[b,i,c] = relu( VW[b,0,i,c] + sum_{j,l} A[b,i,j,l] * VW[b,l+1,j,c] )
// VW[b,l,j,c] = sum_f V[b,j,f] h[l,c,f]
// K2 key fact: flattening A's (j,l) axes gives contiguous K=4096 with k=j*4+l.
// R5: back to LDS staging (R4 proved direct gathers are TA-bound). New tiling:
// c-tile=256 (A read ONCE), 8-wave blocks, k-split 8 -> 16 waves/CU (4/SIMD).
// Runtime-adaptive KT=8/4 on ws_size (partials: KT*4MB bf16).

typedef float          f32x4  __attribute__((ext_vector_type(4)));
typedef __bf16         bf16x8 __attribute__((ext_vector_type(8)));
typedef unsigned short u16x4  __attribute__((ext_vector_type(4)));
typedef unsigned int   u32x4  __attribute__((ext_vector_type(4)));

#define DEV __device__ __forceinline__

DEV void glds16(const void* g, void* l) {
  __builtin_amdgcn_global_load_lds((const __attribute__((address_space(1))) void*)g,
                                   (__attribute__((address_space(3))) void*)l,
                                   16, 0, 0);
}

DEV void cvt8(__bf16* d, f32x4 u, f32x4 v) {
  bf16x8 o;
  o[0]=(__bf16)u[0]; o[1]=(__bf16)u[1]; o[2]=(__bf16)u[2]; o[3]=(__bf16)u[3];
  o[4]=(__bf16)v[0]; o[5]=(__bf16)v[1]; o[6]=(__bf16)v[2]; o[7]=(__bf16)v[3];
  *(bf16x8*)d = o;
}

DEV unsigned short bfbits(float x) {
  return __builtin_bit_cast(unsigned short, (__bf16)x);
}

// ---------------------------------------------------------------------------
// K1: VW projection.  Per block: (b, j-tile 128, c-tile 64), all 5 l.
// Writes W2t[b][c][j*4 + (l-1)] bf16 and VW0[b][j][c] f32.  (unchanged)
// ---------------------------------------------------------------------------
__global__ __launch_bounds__(512, 2)
void k1_vw(const float* __restrict__ Vg, const float* __restrict__ Hg,
           unsigned short* __restrict__ W2t, float* __restrict__ VW0)
{
  __shared__ __attribute__((aligned(16))) __bf16 Vs[2][128*64];
  __shared__ __attribute__((aligned(16))) __bf16 Hs[2][320*64];

  const int tid  = threadIdx.x;
  const int lane = tid & 63;
  const int wid  = tid >> 6;
  const int wj   = wid >> 1;
  const int wc   = wid & 1;
  const int li   = lane & 15;
  const int lg   = lane >> 4;

  const int bid = blockIdx.x;
  const int ct  = bid & 3;
  const int jt  = (bid >> 2) & 7;
  const int b   = bid >> 5;
  const int j0  = jt * 128;
  const int c0  = ct * 64;

  const float* sptr[7];
  int sdst[7];
#pragma unroll
  for (int r = 0; r < 2; ++r) {
    int n = r*512 + tid, row = n >> 3, q = n & 7;
    sptr[r] = Vg + (size_t)(b*1024 + j0 + row)*256 + q*8;
    sdst[r] = row*64 + ((q ^ (row & 7))*8);
  }
#pragma unroll
  for (int r = 0; r < 5; ++r) {
    int n = r*512 + tid, row = n >> 3, q = n & 7;
    int l = row >> 6, cl = row & 63;
    sptr[2+r] = Hg + (size_t)(l*256 + c0 + cl)*256 + q*8;
    sdst[2+r] = row*64 + ((q ^ (row & 7))*8);
  }

  f32x4 acc[5][2][2];
#pragma unroll
  for (int l=0;l<5;l++)
#pragma unroll
    for (int x=0;x<2;x++)
#pragma unroll
      for (int y=0;y<2;y++) acc[l][x][y] = (f32x4){0.f,0.f,0.f,0.f};

  {
    f32x4 sa[14];
#pragma unroll
    for (int i=0;i<7;i++) { sa[2*i] = *(const f32x4*)(sptr[i]); sa[2*i+1] = *(const f32x4*)(sptr[i]+4); }
#pragma unroll
    for (int i=0;i<7;i++) {
      __bf16* d = (i < 2) ? &Vs[0][sdst[i]] : &Hs[0][sdst[i]];
      cvt8(d, sa[2*i], sa[2*i+1]);
    }
  }
  __syncthreads();

  int cur = 0;
#pragma unroll 1
  for (int t = 0; t < 4; ++t) {
    const int nxt = cur ^ 1;
    f32x4 sa[14];
    if (t < 3) {
      const int ko = (t+1)*64;
#pragma unroll
      for (int i=0;i<7;i++) { sa[2*i] = *(const f32x4*)(sptr[i]+ko); sa[2*i+1] = *(const f32x4*)(sptr[i]+ko+4); }
    }
    const __bf16* Vsc = &Vs[cur][0];
    const __bf16* Hsc = &Hs[cur][0];
#pragma unroll
    for (int ks = 0; ks < 2; ++ks) {
      bf16x8 hf[10], vf[2];
#pragma unroll
      for (int l=0;l<5;l++)
#pragma unroll
        for (int cm=0;cm<2;cm++) {
          int row = l*64 + wc*32 + cm*16 + li;
          int ch  = (ks*4 + lg) ^ (row & 7);
          hf[l*2+cm] = *(const bf16x8*)(Hsc + row*64 + ch*8);
        }
#pragma unroll
      for (int jn=0;jn<2;jn++) {
        int row = wj*32 + jn*16 + li;
        int ch  = (ks*4 + lg) ^ (row & 7);
        vf[jn] = *(const bf16x8*)(Vsc + row*64 + ch*8);
      }
#pragma unroll
      for (int l=0;l<5;l++)
#pragma unroll
        for (int cm=0;cm<2;cm++)
#pragma unroll
          for (int jn=0;jn<2;jn++)
            acc[l][cm][jn] = __builtin_amdgcn_mfma_f32_16x16x32_bf16(
                hf[l*2+cm], vf[jn], acc[l][cm][jn], 0, 0, 0);
    }
    if (t < 3) {
#pragma unroll
      for (int i=0;i<7;i++) {
        __bf16* d = (i < 2) ? &Vs[nxt][sdst[i]] : &Hs[nxt][sdst[i]];
        cvt8(d, sa[2*i], sa[2*i+1]);
      }
    }
    __syncthreads();
    cur = nxt;
  }

#pragma unroll
  for (int cm=0;cm<2;cm++)
#pragma unroll
    for (int r=0;r<4;r++) {
      const int c = c0 + wc*32 + cm*16 + lg*4 + r;
#pragma unroll
      for (int jn=0;jn<2;jn++) {
        const int j = j0 + wj*32 + jn*16 + li;
        u16x4 pk;
        pk[0] = bfbits(acc[1][cm][jn][r]);
        pk[1] = bfbits(acc[2][cm][jn][r]);
        pk[2] = bfbits(acc[3][cm][jn][r]);
        pk[3] = bfbits(acc[4][cm][jn][r]);
        *(u16x4*)(W2t + (size_t)(b*256 + c)*4096 + (size_t)j*4) = pk;
        VW0[(size_t)(b*1024 + j)*256 + c] = acc[0][cm][jn][r];
      }
    }
}

// ---------------------------------------------------------------------------
// K2: partial[kt][b][i][c] = sum_{k in chunk} A[b][i][k] * W2t[b][c][k]
// Tile 128(i) x 256(c, full), k-split KT. Block: 512 thr = 8 waves (2i x 4c),
// wave = 64i x 64c = 4x4 frags, 16 MFMA/step. K-step 32.
// A: reg-stage f32->bf16 -> ds_write (coalesced 128B/row-quad loads).
// B: global_load_lds, pre-swizzled source. LDS 48KB dbuf. One barrier/step.
// Grid (KT=8): 8b x 8it x 8kt = 512 blocks -> 2 blk/CU x 8 waves = 4 waves/SIMD.
// XCD swizzle: batch b == XCD id (A/B L2/L3 locality).
// Swizzle: LDS chunk position q holds GLOBAL chunk q^s, s=(row>>1)&3 (2-way max).
// ---------------------------------------------------------------------------
template<int KT>
__global__ __launch_bounds__(512, 4)
void k2_gemm(const float* __restrict__ Ag, const unsigned short* __restrict__ W2t,
             unsigned short* __restrict__ part)
{
  __shared__ __attribute__((aligned(16))) __bf16 As[2][128*32];  // 2 x 8 KB
  __shared__ __attribute__((aligned(16))) __bf16 Bs[2][256*32];  // 2 x 16 KB

  constexpr int KCH   = 4096 / KT;   // k per block
  constexpr int NSTEP = KCH / 32;

  const int tid  = threadIdx.x;
  const int lane = tid & 63;
  const int wid  = tid >> 6;   // 0..7
  const int wi   = wid >> 2;   // 0..1 (i 64-strips)
  const int wc   = wid & 3;    // 0..3 (c 64-strips)
  const int li   = lane & 15;
  const int lg   = lane >> 4;

  // XCD swizzle: physical p -> logical bid; XCD (p&7) owns batch b=(p&7).
  const int p   = blockIdx.x;                 // 64*KT blocks
  const int bid = (p & 7) * (8*KT) + (p >> 3);
  const int kt  = bid % KT;
  const int it  = (bid / KT) & 7;
  const int b   = bid / (8*KT);

  const int i0 = it*128, k0 = kt*KCH;

  // A staging: 1 chunk/thread (8 f32 -> 8 bf16). chunk n=tid: row=n>>2, q=n&3.
  const int arow = tid >> 2, aq = tid & 3;
  const float* asrc = Ag + (size_t)(b*1024 + i0 + arow)*4096 + k0 + aq*8;
  const int ad = arow*32 + ((aq ^ ((arow >> 1) & 3))*8);

  // B staging via glds: 2 rounds. chunk n=r*512+tid: row=n>>2, q=n&3.
  const unsigned short *bsrc0, *bsrc1;
  {
    int n, row, q;
    n = tid;        row = n>>2; q = n&3;
    bsrc0 = W2t + (size_t)(b*256 + row)*4096 + k0 + ((q ^ ((row>>1)&3))*8);
    n = 512 + tid;  row = n>>2; q = n&3;
    bsrc1 = W2t + (size_t)(b*256 + row)*4096 + k0 + ((q ^ ((row>>1)&3))*8);
  }
  const int bd0 = wid*512;          // elems; wave-uniform base, HW adds lane*16B
  const int bd1 = 4096 + wid*512;

  f32x4 acc[4][4];
#pragma unroll
  for (int m=0;m<4;m++)
#pragma unroll
    for (int n=0;n<4;n++) acc[m][n] = (f32x4){0.f,0.f,0.f,0.f};

  // prologue: stage step 0 into buf 0
  {
    f32x4 a0 = *(const f32x4*)asrc, a1 = *(const f32x4*)(asrc+4);
    glds16(bsrc0, &Bs[0][bd0]);
    glds16(bsrc1, &Bs[0][bd1]);
    cvt8(&As[0][ad], a0, a1);
  }
  __syncthreads();

  int cur = 0;
#pragma unroll 1
  for (int t = 0; t < NSTEP; ++t) {
    const int nxt = cur ^ 1;
    f32x4 a0, a1;
    if (t < NSTEP-1) {
      const int o = (t+1)*32;
      a0 = *(const f32x4*)(asrc + o);
      a1 = *(const f32x4*)(asrc + o + 4);
      glds16(bsrc0 + o, &Bs[nxt][bd0]);
      glds16(bsrc1 + o, &Bs[nxt][bd1]);
    }
    {
      bf16x8 af[4], bfv[4];
#pragma unroll
      for (int m=0;m<4;m++) {
        int row = wi*64 + m*16 + li;
        int ch  = lg ^ ((row >> 1) & 3);
        af[m] = *(const bf16x8*)(&As[cur][row*32 + ch*8]);
      }
#pragma unroll
      for (int n=0;n<4;n++) {
        int row = wc*64 + n*16 + li;
        int ch  = lg ^ ((row >> 1) & 3);
        bfv[n] = *(const bf16x8*)(&Bs[cur][row*32 + ch*8]);
      }
#pragma unroll
      for (int m=0;m<4;m++)
#pragma unroll
        for (int n=0;n<4;n++)
          acc[m][n] = __builtin_amdgcn_mfma_f32_16x16x32_bf16(af[m], bfv[n], acc[m][n], 0, 0, 0);
    }
    if (t < NSTEP-1) cvt8(&As[nxt][ad], a0, a1);
    __syncthreads();
    cur = nxt;
  }

  // epilogue -> bf16 partial plane
  unsigned short* pb = part + (size_t)kt*2097152u + (size_t)(b*1024 + i0)*256;
#pragma unroll
  for (int m=0;m<4;m++)
#pragma unroll
    for (int r=0;r<4;r++) {
      const int il = wi*64 + m*16 + lg*4 + r;
#pragma unroll
      for (int n=0;n<4;n++) {
        const int cl = wc*64 + n*16 + li;
        pb[(size_t)il*256 + cl] = bfbits(acc[m][n][r]);
      }
    }
}

// ---------------------------------------------------------------------------
// K3: out = relu(VW0 + sum_{kt} partial[kt]), 8 elems/thread
// ---------------------------------------------------------------------------
template<int NP>
__global__ __launch_bounds__(256)
void k3_reduce(const unsigned short* __restrict__ part, const float* __restrict__ VW0,
               float* __restrict__ out)
{
  const size_t i8 = ((size_t)blockIdx.x*256 + threadIdx.x)*8;
  f32x4 s0 = *(const f32x4*)(VW0 + i8);
  f32x4 s1 = *(const f32x4*)(VW0 + i8 + 4);
#pragma unroll
  for (int p=0;p<NP;p++) {
    u32x4 u = *(const u32x4*)(part + (size_t)p*2097152u + i8);
    s0[0] += __uint_as_float(u[0] << 16);  s0[1] += __uint_as_float(u[0] & 0xffff0000u);
    s0[2] += __uint_as_float(u[1] << 16);  s0[3] += __uint_as_float(u[1] & 0xffff0000u);
    s1[0] += __uint_as_float(u[2] << 16);  s1[1] += __uint_as_float(u[2] & 0xffff0000u);
    s1[2] += __uint_as_float(u[3] << 16);  s1[3] += __uint_as_float(u[3] & 0xffff0000u);
  }
#pragma unroll
  for (int e=0;e<4;e++){ s0[e] = fmaxf(s0[e],0.f); s1[e] = fmaxf(s1[e],0.f); }
  *(f32x4*)(out + i8)     = s0;
  *(f32x4*)(out + i8 + 4) = s1;
}

// ---------------------------------------------------------------------------
extern "C" void kernel_launch(void* const* d_in, const int* in_sizes, int n_in,
                              void* d_out, int out_size, void* d_ws, size_t ws_size,
                              hipStream_t stream) {
  const float* Vg = (const float*)d_in[0];   // (8,1024,256) f32
  const float* Ag = (const float*)d_in[1];   // (8,1024,1024,4) f32
  const float* Hg = (const float*)d_in[2];   // (5,256,256) f32
  float* out = (float*)d_out;                // (8,1024,256) f32

  // ws: W2t bf16 16MB | VW0 f32 8MB | partials bf16 KT*4MB
  if (ws_size < 41943040u) return;
  char* ws = (char*)d_ws;
  unsigned short* W2t  = (unsigned short*)(ws);
  float*          VW0  = (float*)(ws + 16777216u);
  unsigned short* part = (unsigned short*)(ws + 16777216u + 8388608u);

  const bool big = (ws_size >= 58720256u);   // 16+8+32 MB for KT=8

  k1_vw<<<dim3(256), dim3(512), 0, stream>>>(Vg, Hg, W2t, VW0);
  if (big) {
    k2_gemm<8><<<dim3(512), dim3(512), 0, stream>>>(Ag, W2t, part);
    k3_reduce<8><<<dim3(1024), dim3(256), 0, stream>>>(part, VW0, out);
  } else {
    k2_gemm<4><<<dim3(256), dim3(512), 0, stream>>>(Ag, W2t, part);
    k3_reduce<4><<<dim3(1024), dim3(256), 0, stream>>>(part, VW0, out);
  }
}